// Round 6
// baseline (260.150 us; speedup 1.0000x reference)
//
#include <hip/hip_runtime.h>
#include <math.h>

// GAU attention: LN -> silu(x@W^T+b) x4 -> P=relu^2(QK^T/sqrt(T)) -> AV=P@V -> (U*AV)@Wo^T+bo
// R17 == R16 resubmitted verbatim (R16's bench failed at container acquisition —
// infra error, no kernel verdict; source re-audited, no hang-capable defect found).
// R16: accounting across R11-R15 shows pre_kernel is ~25-35us (2B scatter-store
// write amplification into the pL pack: each 64B line receives 16B, neighbors are
// in other blocks/XCDs) and staged 'out' (~50us, 384 blocks 1.5/CU latency-bound)
// lost to R11's streaming out (~25us, 768 barrier-free blocks).
//  - pre: both pack writes now 1 short8 (16B contiguous frag-row) per thread.
//  - out: reverted to R0 streaming kernel verbatim (barrier-free, dist-2 ping-pong).
//  - QKVU: R13 2-phase staged 128x128 (measured 52.7us). P: 8-phase 256x256.
//    G: staged TN=4 (fit: 52 staged < ~67 streaming). Unchanged.

typedef __attribute__((ext_vector_type(8))) short short8;
typedef __attribute__((ext_vector_type(4))) short short4v;
typedef __attribute__((ext_vector_type(4))) float floatx4;

constexpr int HD = 768;
constexpr int TT = 2048;
constexpr long WElem = 589824;     // 768*768
constexpr long QKpb  = 1572864;    // 2048*768 shorts per batch
constexpr long Ppb   = 4194304;    // 2048*2048 shorts per batch

__device__ __forceinline__ short f2bf(float x) {
  unsigned u = __builtin_bit_cast(unsigned, x);
  u = u + 0x7fffu + ((u >> 16) & 1u);   // RNE
  return (short)(u >> 16);
}
__device__ __forceinline__ float bf2f(short s) {
  unsigned u = ((unsigned)(unsigned short)s) << 16;
  return __builtin_bit_cast(float, u);
}

// kf-major packed offset (in shorts) of element (i, c) of a row-major [R x C]
// matrix, KF = C/32. Layout: [strip = i>>6][kf = c>>5][frag mi = (i>>4)&3][512].
// Within-frag: lane = ((c&31)>>3)*16 + (i&15), elem = c&7.
__device__ __forceinline__ long pL(int i, int c, int KF) {
  return (((long)(i >> 6) * KF + (c >> 5)) * 4 + ((i >> 4) & 3)) * 512 +
         ((c & 31) >> 3) * 128 + (i & 15) * 8 + (c & 7);
}

typedef __attribute__((address_space(1))) void void_g;
typedef __attribute__((address_space(3))) void void_l;
__device__ __forceinline__ void gload16(const void* g, void* l) {
  __builtin_amdgcn_global_load_lds((const void_g*)g, (void_l*)l, 16, 0, 0);
}

// ---------------- merged preprocessing: LN(+pack) and weight convert ---------------
// blocks [0, 8192): LayerNorm rows (vectorized short8 pack writes);
// blocks [8192, 9632): fp32->bf16 weight pack, 8 elems (one 16B frag-row) per thread.
__global__ __launch_bounds__(256) void pre_kernel(
    const float* __restrict__ x, const float* __restrict__ g,
    const float* __restrict__ b, short* __restrict__ out,
    const float* __restrict__ wu, const float* __restrict__ wq,
    const float* __restrict__ wk, const float* __restrict__ wv,
    const float* __restrict__ wo,
    const float* __restrict__ bu, const float* __restrict__ bq,
    const float* __restrict__ bk, const float* __restrict__ bv,
    short* __restrict__ Wb, float* __restrict__ bcat) {
  int t = threadIdx.x;
  if (blockIdx.x < 8192) {
    int row = blockIdx.x;
    const float* xr = x + (long)row * HD;
    float v0 = xr[t], v1 = xr[t + 256], v2 = xr[t + 512];
    float s = v0 + v1 + v2;
    float ss = v0 * v0 + v1 * v1 + v2 * v2;
#pragma unroll
    for (int o = 32; o > 0; o >>= 1) {
      s += __shfl_down(s, o);
      ss += __shfl_down(ss, o);
    }
    __shared__ float red[8];
    int wid = t >> 6;
    if ((t & 63) == 0) { red[wid] = s; red[4 + wid] = ss; }
    __syncthreads();
    float S = red[0] + red[1] + red[2] + red[3];
    float SS = red[4] + red[5] + red[6] + red[7];
    float mean = S * (1.0f / HD);
    float var = SS * (1.0f / HD) - mean * mean;
    float rstd = rsqrtf(var + 1e-5f);
    // vectorized pack write: threads 0..95 each own 8 consecutive cols (L1-hot reload)
    if (t < 96) {
      int c0 = t * 8;
      short8 pk;
#pragma unroll
      for (int j = 0; j < 8; j++)
        pk[j] = f2bf((xr[c0 + j] - mean) * rstd * g[c0 + j] + b[c0 + j]);
      *(short8*)&out[pL(row, c0, 24)] = pk;
    }
  } else {
    long ci = (long)(blockIdx.x - 8192) * 256 + t;   // 16B-chunk index
    if (ci < 5 * WElem / 8) {
      long i = ci * 8;
      int which = (int)(i / WElem);
      long off = i - (long)which * WElem;
      const float* src = which == 0 ? wu : which == 1 ? wq : which == 2 ? wk
                       : which == 3 ? wv : wo;
      int n = (int)(off / HD), k = (int)(off - (long)n * HD);   // k % 8 == 0
      short8 pk;
#pragma unroll
      for (int j = 0; j < 8; j++) pk[j] = f2bf(src[off + j]);
      *(short8*)&Wb[(long)which * WElem + pL(n, k, 24)] = pk;
    }
    if (ci < 4 * HD) {
      int which = (int)(ci / HD);
      int off = (int)(ci - which * HD);
      const float* src = which == 0 ? bu : which == 1 ? bq : which == 2 ? bk : bv;
      bcat[ci] = src[off];
    }
  }
}

// ---------------- 256x256 8-phase GEMM (P only) ------------------------------------
// 8 waves 2x4 (wm,wn); wave tile 128x64: acc[8][4]; BK=64 = 2 kf.
// LDS: A[p][strip 0..3][k 0..1][fi 0..3][1024B] at 0 / 32KB; B same at 64KB / 96KB.
template <int EPI, int KF, int GZ, int GY>
__global__ __launch_bounds__(512, 2) void wgemm8(
    const short* __restrict__ Ag, const short* __restrict__ Bg,
    long sAz, long sBz, short* __restrict__ o0) {
  constexpr int NT = KF / 2;                 // K-tiles
  constexpr int GYX = (GZ == 1) ? GY / 8 : GY / 2;
  int f = blockIdx.x;
  int xcd = f & 7, i = f >> 3;
  int bx = i / GYX, byo = i % GYX;
  int z, by;
  if constexpr (GZ == 1) { z = 0;        by = xcd * GYX + byo; }
  else                   { z = xcd >> 1; by = (xcd & 1) * GYX + byo; }

  int t = threadIdx.x, w = t >> 6, lane = t & 63;
  int wm = w >> 2, wn = w & 3;
  int qd = lane >> 4, l15 = lane & 15;
  int mf0 = by * 16 + wm * 8;                // frag-row base (16 frags/block)
  int nf0 = bx * 16 + wn * 4;                // frag-col base

  __shared__ __align__(16) char smem[131072];

  const char* Ab = (const char*)(Ag + (long)z * sAz);
  const char* Bb = (const char*)(Bg + (long)z * sBz);
  const char* aGt = Ab + ((long)(by * 4 + wm) * KF) * 4096 + wn * 1024 + lane * 16;
  const char* bGt = Bb + ((long)(bx * 4 + wm) * KF) * 4096 + wn * 1024 + lane * 16;
  char* ldsAst = smem + (wm * 8 + wn) * 1024;
  char* ldsBst = smem + 65536 + (wm * 8 + wn) * 1024;
  const char* rA = smem + wm * 16384 + lane * 16;
  const char* rB = smem + 65536 + wn * 8192 + lane * 16;

#define STG(which, p, k, kfg)                                                 \
  {                                                                           \
    const char* sb_ = (which) ? bGt : aGt;                                    \
    char* db_ = ((which) ? ldsBst : ldsAst) + (p) * 32768 + (k) * 4096;       \
    gload16(sb_ + (long)(kfg) * 4096, db_);                                   \
    gload16(sb_ + ((long)(2 * KF) + (kfg)) * 4096, db_ + 16384);              \
  }

#define PH(p, h, k, VM, ...)                                                  \
  {                                                                           \
    short8 aq[4];                                                             \
    if ((h) == 0) {                                                           \
      _Pragma("unroll") for (int ni = 0; ni < 4; ni++)                        \
          bq[ni] = *(const short8*)(rB + (p) * 32768 + (k) * 4096 + ni * 1024); \
    }                                                                         \
    _Pragma("unroll") for (int m2 = 0; m2 < 4; m2++)                          \
        aq[m2] = *(const short8*)(rA + (p) * 32768 + (h) * 8192 +             \
                                  (k) * 4096 + m2 * 1024);                    \
    __VA_ARGS__;                                                              \
    __builtin_amdgcn_s_barrier();                                             \
    asm volatile("s_waitcnt lgkmcnt(0)" ::: "memory");                        \
    __builtin_amdgcn_sched_barrier(0);                                        \
    __builtin_amdgcn_s_setprio(1);                                            \
    _Pragma("unroll") for (int ni = 0; ni < 4; ni++)                          \
      _Pragma("unroll") for (int m2 = 0; m2 < 4; m2++)                        \
          acc[(h) * 4 + m2][ni] = __builtin_amdgcn_mfma_f32_16x16x32_bf16(    \
              aq[m2], bq[ni], acc[(h) * 4 + m2][ni], 0, 0, 0);                \
    __builtin_amdgcn_s_setprio(0);                                            \
    __builtin_amdgcn_sched_barrier(0);                                        \
    VM;                                                                       \
    __builtin_amdgcn_s_barrier();                                             \
  }

  floatx4 acc[8][4] = {};
  short8 bq[4];

  STG(0, 0, 0, 0); STG(1, 0, 0, 0); STG(0, 0, 1, 1); STG(1, 0, 1, 1);
  asm volatile("s_waitcnt vmcnt(4)" ::: "memory");
  __builtin_amdgcn_s_barrier();

#pragma unroll 2
  for (int kt = 0; kt < NT - 1; ++kt) {
    int p = kt & 1, q = p ^ 1;
    int kfg = (kt + 1) * 2;
    PH(p, 0, 0, , STG(0, q, 0, kfg));
    PH(p, 1, 0, asm volatile("s_waitcnt vmcnt(4)" ::: "memory"), STG(1, q, 0, kfg));
    PH(p, 0, 1, , STG(0, q, 1, kfg + 1));
    PH(p, 1, 1, asm volatile("s_waitcnt vmcnt(4)" ::: "memory"), STG(1, q, 1, kfg + 1));
  }
  {
    int p = (NT - 1) & 1;
    PH(p, 0, 0, , );
    PH(p, 1, 0, asm volatile("s_waitcnt vmcnt(0)" ::: "memory"), );
    PH(p, 0, 1, , );
    PH(p, 1, 1, , );
  }
#undef PH
#undef STG

  // ---- epilogue (EPI==1): P = relu(S/sqrt(T))^2, packed vectorized store ----
  int qd4 = qd * 4;
  short* scw = (short*)(smem + w * 16384);   // 32 tiles x 512B
#pragma unroll
  for (int mi = 0; mi < 8; mi++)
#pragma unroll
    for (int ni = 0; ni < 4; ni++) {
      short* tile = scw + (mi * 4 + ni) * 256;
#pragma unroll
      for (int r = 0; r < 4; r++) {
        float v = acc[mi][ni][r];
        v *= 0.022097086912079608f;           // 1/sqrt(2048)
        v = fmaxf(v, 0.0f);
        v = v * v;
        tile[(qd4 + r) * 16 + (l15 ^ (((qd4 + r) & 4) << 1))] = f2bf(v);
      }
    }
  __syncthreads();
  int rw = lane & 15, g = (lane >> 4) & 1;
#pragma unroll
  for (int fp = 0; fp < 16; fp++) {
    int id = fp * 2 + (lane >> 5);
    int mi = id >> 2, ni = id & 3;
    const short* tile = scw + id * 256;
    short8 val = *(const short8*)&tile[rw * 16 + ((g ^ ((rw >> 2) & 1)) << 3)];
    int m = (mf0 + mi) * 16 + rw;
    int c0 = (nf0 + ni) * 16 + g * 8;
    *(short8*)&o0[(long)z * Ppb + pL(m, c0, 64)] = val;
  }
}

// ---------------- LDS-staged GEMM (m97 structure), EPI 0 (QKVU) / 2 (G) ------------
// 4 waves 2x2; wave tile 64x64 (TM=TN=4); block 128x128.
template <int EPI, int KF, int GZ, int TN, int WN, int GY>
__global__ __launch_bounds__(256, 3) void wgemm(
    const short* __restrict__ Ag, const short* __restrict__ Bg,
    long sAz, long sBz,
    short* __restrict__ o0, short* __restrict__ o1,
    short* __restrict__ o2, short* __restrict__ o3,
    float* __restrict__ outf, const float* __restrict__ bias,
    const short* __restrict__ umul) {
  constexpr int TM = 4;
  constexpr int WM = 4 / WN;                 // 2
  constexpr int NSA = WM * TM / 4;           // 2 strips (BM = 128 rows)
  constexpr int NSB = WN * TN / 4;           // 2 strips (BN = 128 cols)
  static_assert(TN == 4, "epilogue assumes TN=4");
  constexpr int LDSA_B = NSA * 4096 * 2;     // 16 KB (2 buffers)
  constexpr int LDSB_B = NSB * 4096 * 2;     // 16 KB
  constexpr int GYX = (GZ == 1) ? GY / 8 : GY / 2;   // by-range per XCD
  int f = blockIdx.x;
  int xcd = f & 7, i = f >> 3;
  int bx = i / GYX, byo = i % GYX;
  int z, by;
  if constexpr (GZ == 1) { z = 0;        by = xcd * GYX + byo; }
  else                   { z = xcd >> 1; by = (xcd & 1) * GYX + byo; }

  int t = threadIdx.x, w = t >> 6, lane = t & 63;
  int qd = lane >> 4, l15 = lane & 15;
  int wm = w / WN, wn = w % WN;
  int mf0 = (by * WM + wm) * TM;               // frag-row index
  int nf0 = (bx * WN + wn) * TN;               // frag-col index

  __shared__ __align__(16) char smem[LDSA_B + LDSB_B];   // 32 KB

  const char* aG = (const char*)(Ag + (long)z * sAz) +
                   (long)(by * NSA) * KF * 4096 + w * 1024 + lane * 16;
  const char* bG = (const char*)(Bg + (long)z * sBz) +
                   (long)(bx * NSB) * KF * 4096 + w * 1024 + lane * 16;
  char* lA0 = smem + w * 1024;
  char* lB0 = smem + LDSA_B + w * 1024;

#define STAGE(p, kf)                                                          \
  {                                                                           \
    _Pragma("unroll") for (int s = 0; s < NSA; s++)                           \
        gload16(aG + ((long)s * KF + (kf)) * 4096,                            \
                lA0 + (p) * (NSA * 4096) + s * 4096);                         \
    _Pragma("unroll") for (int s = 0; s < NSB; s++)                           \
        gload16(bG + ((long)s * KF + (kf)) * 4096,                            \
                lB0 + (p) * (NSB * 4096) + s * 4096);                         \
  }

  floatx4 acc[TM][TN] = {};
  const char* fA = smem + (wm * TM) * 1024 + lane * 16;
  const char* fB = smem + LDSA_B + (wn * TN) * 1024 + lane * 16;

  STAGE(0, 0);
  __syncthreads();
#pragma unroll 2
  for (int kf = 0; kf < KF; ++kf) {
    int p = kf & 1;
    if (kf + 1 < KF) STAGE(p ^ 1, kf + 1);
    short8 a[TM], b[TN];
#pragma unroll
    for (int mi = 0; mi < TM; mi++)
      a[mi] = *(const short8*)(fA + p * (NSA * 4096) + mi * 1024);
#pragma unroll
    for (int ni = 0; ni < TN; ni++)
      b[ni] = *(const short8*)(fB + p * (NSB * 4096) + ni * 1024);
#pragma unroll
    for (int ni = 0; ni < TN; ni++)
#pragma unroll
      for (int mi = 0; mi < TM; mi++)
        acc[mi][ni] = __builtin_amdgcn_mfma_f32_16x16x32_bf16(
            a[mi], b[ni], acc[mi][ni], 0, 0, 0);
    __syncthreads();
  }
#undef STAGE

  // ---- epilogue ----
  int qd4 = qd * 4;
  if constexpr (EPI == 0) {
    short* scw = (short*)(smem + w * 8192);        // 16 tiles x 512 B
    const bool vt = (bx >= 18);                    // which==3 (V): transposed tiles
#pragma unroll
    for (int mi = 0; mi < TM; mi++)
#pragma unroll
      for (int ni = 0; ni < TN; ni++) {
        int col = (nf0 + ni) * 16 + l15;
        short* tile = scw + (mi * TN + ni) * 256;
        short4v pk;
#pragma unroll
        for (int r = 0; r < 4; r++) {
          float v = acc[mi][ni][r];
          v += bias[col];
          v = v / (1.0f + __expf(-v));            // silu
          short sv = f2bf(v);
          if (!vt) tile[(qd4 + r) * 16 + (l15 ^ (((qd4 + r) & 4) << 1))] = sv;
          else pk[r] = sv;
        }
        if (vt)   // transposed tile[col][row]; rows qd4..qd4+3 contiguous -> b64
          *(short4v*)&tile[l15 * 16 + (qd4 ^ ((l15 & 4) << 1))] = pk;
      }
    __syncthreads();
    int rw = lane & 15, g = (lane >> 4) & 1;
#pragma unroll
    for (int fp = 0; fp < 8; fp++) {
      int id = fp * 2 + (lane >> 5);
      int mi = id >> 2, ni = id & 3;
      const short* tile = scw + id * 256;
      short8 val = *(const short8*)&tile[rw * 16 + ((g ^ ((rw >> 2) & 1)) << 3)];
      if (!vt) {
        int m = (mf0 + mi) * 16 + rw;
        int c0 = (nf0 + ni) * 16 + g * 8;
        int which = bx / 6;                      // block-uniform
        int d0 = c0 - which * HD;
        int batch = m >> 11, ii = m & (TT - 1);
        if (which == 0)      *(short8*)&o0[(long)m * HD + d0] = val;
        else if (which == 1) *(short8*)&o1[(long)batch * QKpb + pL(ii, d0, 24)] = val;
        else                 *(short8*)&o2[(long)batch * QKpb + pL(ii, d0, 24)] = val;
      } else {
        int d = (nf0 + ni) * 16 + rw - 3 * HD;   // tile row = original col
        int m0 = (mf0 + mi) * 16 + g * 8;        // 8 consecutive output rows
        int batch = m0 >> 11, ii0 = m0 & (TT - 1);
        *(short8*)&o3[(long)batch * QKpb + pL(d, ii0, 64)] = val;
      }
    }
  } else {
    // EPI 2: f32 scratch (no early rounding), two passes of 8 frags (8 KB/wave)
    float* scf = (float*)(smem + w * 8192);
#pragma unroll
    for (int half = 0; half < 2; half++) {
#pragma unroll
      for (int mi2 = 0; mi2 < 2; mi2++)
#pragma unroll
        for (int ni = 0; ni < TN; ni++) {
          float* tile = scf + (mi2 * TN + ni) * 256;
          int mi = half * 2 + mi2;
#pragma unroll
          for (int r = 0; r < 4; r++)
            tile[(qd4 + r) * 16 + (l15 ^ (((qd4 + r) & 4) << 1))] = acc[mi][ni][r];
        }
      __syncthreads();
      int rw = lane & 15, g4 = lane >> 4;
#pragma unroll
      for (int cp = 0; cp < 8; cp++) {
        int mi = half * 2 + (cp >> 2), ni = cp & 3;
        const float* tile = scf + cp * 256;
        floatx4 val = *(const floatx4*)&tile[rw * 16 + ((g4 ^ (((rw >> 2) & 1) << 1)) << 2)];
        int m = (mf0 + mi) * 16 + rw;
        int c0 = (nf0 + ni) * 16 + g4 * 4;
        long gm = (long)z * TT + m;
        short4v u = *(const short4v*)&umul[gm * HD + c0];
        short4v gv;
#pragma unroll
        for (int j = 0; j < 4; j++) gv[j] = f2bf(val[j] * bf2f(u[j]));
        *(short4v*)&o0[pL((int)gm, c0, 24)] = gv;
      }
      __syncthreads();
    }
  }
  (void)outf;
}

// ---------------- barrier-free streaming GEMM (R0 verbatim) — 'out' only -----------
// 4 waves WM x WN; wave tile 64 x (TN*16); dist-2 ping-pong; ni-outer MFMA.
template <int EPI, int KF, int GZ, int TN, int WN, int GY>
__global__ __launch_bounds__(256, 3) void sgemm(
    const short* __restrict__ Ag, const short* __restrict__ Bg,
    long sAz, long sBz,
    short* __restrict__ o0, short* __restrict__ o1,
    short* __restrict__ o2, short* __restrict__ o3,
    float* __restrict__ outf, const float* __restrict__ bias,
    const short* __restrict__ umul) {
  constexpr int TM = 4;
  constexpr int WM = 4 / WN;
  constexpr int GYX = (GZ == 1) ? GY / 8 : GY / 2;   // by-range per XCD
  int f = blockIdx.x;
  int xcd = f & 7, i = f >> 3;
  int bx = i / GYX, byo = i % GYX;
  int z, by;
  if constexpr (GZ == 1) { z = 0;        by = xcd * GYX + byo; }
  else                   { z = xcd >> 1; by = (xcd & 1) * GYX + byo; }

  int t = threadIdx.x, w = t >> 6, lane = t & 63;
  int qd = lane >> 4, l15 = lane & 15;
  int wm = w / WN, wn = w % WN;
  int mf0 = (by * WM + wm) * TM;               // frag-row index (strip-aligned)
  int nf0 = (bx * WN + wn) * TN;               // frag-col index
  const short* aB = Ag + (long)z * sAz + (long)(mf0 >> 2) * KF * 2048 + lane * 8;
  const short* bB = Bg + (long)z * sBz + (long)(nf0 >> 2) * KF * 2048 +
                    (nf0 & 3) * 512 + lane * 8;

  floatx4 acc[TM][TN] = {};
  short8 a[2][TM], b[2][TN];

#define LOADF(p, kf)                                                        \
  {                                                                         \
    _Pragma("unroll") for (int mi = 0; mi < TM; mi++)                       \
        a[p][mi] = *(const short8*)(aB + ((kf) * 4 + mi) * 512);            \
    _Pragma("unroll") for (int ni = 0; ni < TN; ni++)                       \
        b[p][ni] = *(const short8*)(bB + ((kf) * 4 + ni) * 512);            \
  }
#define MFMAS(p)                                                            \
  {                                                                         \
    _Pragma("unroll") for (int ni = 0; ni < TN; ni++)                       \
        _Pragma("unroll") for (int mi = 0; mi < TM; mi++)                   \
            acc[mi][ni] = __builtin_amdgcn_mfma_f32_16x16x32_bf16(          \
                a[p][mi], b[p][ni], acc[mi][ni], 0, 0, 0);                  \
  }

  LOADF(0, 0);
  LOADF(1, 1);
#pragma unroll 2
  for (int kf = 0; kf < KF; ++kf) {
    MFMAS(kf & 1);
    if (kf + 2 < KF) LOADF(kf & 1, kf + 2);   // refill the buffer just consumed
  }
#undef LOADF
#undef MFMAS

  // epilogue: lane holds D[row = qd*4+r][col = l15] per 16x16 frag
#pragma unroll
  for (int mi = 0; mi < TM; mi++)
#pragma unroll
    for (int ni = 0; ni < TN; ni++) {
      int mB = (mf0 + mi) * 16 + qd * 4;
      int col = (nf0 + ni) * 16 + l15;
#pragma unroll
      for (int r = 0; r < 4; r++) {
        int m = mB + r;
        float v = acc[mi][ni][r];
        if constexpr (EPI == 2) {
          long gm = (long)z * TT + m;
          float um = bf2f(umul[gm * HD + col]);
          o0[pL((int)gm, col, 24)] = f2bf(v * um);
        } else {
          outf[(long)m * HD + col] = v + bias[col];
        }
      }
    }
  (void)o1; (void)o2; (void)o3;
}

extern "C" void kernel_launch(void* const* d_in, const int* in_sizes, int n_in,
                              void* d_out, int out_size, void* d_ws, size_t ws_size,
                              hipStream_t stream) {
  (void)in_sizes; (void)n_in; (void)out_size; (void)ws_size;
  const float* hid = (const float*)d_in[0];
  const float* lng = (const float*)d_in[1];
  const float* lnb = (const float*)d_in[2];
  const float* Wu  = (const float*)d_in[3];
  const float* bu  = (const float*)d_in[4];
  const float* Wq  = (const float*)d_in[5];
  const float* bq  = (const float*)d_in[6];
  const float* Wk  = (const float*)d_in[7];
  const float* bk  = (const float*)d_in[8];
  const float* Wv  = (const float*)d_in[9];
  const float* bv  = (const float*)d_in[10];
  const float* Wo  = (const float*)d_in[11];
  const float* bo  = (const float*)d_in[12];

  // workspace layout (bytes); packed buffers
  char* ws = (char*)d_ws;
  short* Wb   = (short*)(ws);                 // 5*589824 bf16 = 5,898,240 B (packed)
  float* bcat = (float*)(ws + 5898240);       // 3072 fp32     =    12,288 B
  short* xbf  = (short*)(ws + 5910528);       // x pack, 12,582,912 B
  short* Ub   = (short*)(ws + 18493440);      // U row-major, 12,582,912 B
  short* Qb   = (short*)(ws + 31076352);      // Q pack, 12,582,912 B
  short* Kb   = (short*)(ws + 43659264);      // K pack, 12,582,912 B
  short* Vt   = (short*)(ws + 56242176);      // Vt pack, 12,582,912 B
  short* Pb   = (short*)(ws + 68825088);      // P pack, 33,554,432 B
  short* Gb   = (short*)(ws + 102379520);     // G pack, 12,582,912 B (total ~115 MB)

  // merged preprocessing: blocks [0,8192) LN, [8192,9632) weight convert (short8)
  pre_kernel<<<9632, 256, 0, stream>>>(hid, lng, lnb, xbf,
      Wu, Wq, Wk, Wv, Wo, bu, bq, bk, bv, Wb, bcat);

  // U,Q,K,V = silu(x @ Wcat^T + bcat): block 128x128 (2x2), GY=64, GX=24
  wgemm<0, 24, 1, 4, 2, 64><<<1536, 256, 0, stream>>>(
      xbf, Wb, 0, 0, Ub, Qb, Kb, Vt, nullptr, bcat, nullptr);

  // P = relu(QK^T/sqrt(T))^2 per batch: 256x256 8-phase, GY=8, GX=8, GZ=4
  wgemm8<1, 24, 4, 8><<<256, 512, 0, stream>>>(
      Qb, Kb, QKpb, QKpb, Pb);

  // G = (P @ V) * U per batch: staged, block 128x128 (2x2, TN=4), GY=16, GX=6, GZ=4
  wgemm<2, 64, 4, 4, 2, 16><<<384, 256, 0, stream>>>(
      Pb, Vt, Ppb, QKpb, Gb, nullptr, nullptr, nullptr, nullptr, nullptr, Ub);

  // out = G @ Wo^T + bo: STREAMING, block 128x64 (2x2, TN=2), GY=64, GX=12, GZ=1
  sgemm<3, 24, 1, 2, 2, 64><<<768, 256, 0, stream>>>(
      Gb, Wb + 4 * WElem, 0, 0, nullptr, nullptr, nullptr, nullptr,
      (float*)d_out, bo, nullptr);
}

// Round 7
// 247.198 us; speedup vs baseline: 1.0524x; 1.0524x over previous
//
#include <hip/hip_runtime.h>
#include <math.h>

// GAU attention: LN -> silu(x@W^T+b) x4 -> P=relu^2(QK^T/sqrt(T)) -> AV=P@V -> (U*AV)@Wo^T+bo
// R18: two independent mechanism fixes (noise floor ~±8us makes finer attribution moot):
//  - pre: R16's short8 stores still left 4x write amplification (four 16B stores per
//    c-oct group land 256B apart; each 64B line gets 16B). Rewritten as 16-row slabs:
//    a full wave writes each 1KB frag as ONE coalesced burst (lane -> byte lane*16).
//    LN stats via 16-lane-group shuffle reduce; weight pack = same path, mean=0/rstd=1.
//  - G: 384 blocks at 3-blocks/CU capacity = half the CUs host 2 blocks -> 25-33% tail.
//    Tile 128x128 -> 64x128 (TM=2): 768 blocks = exactly 3/CU, zero tail.
//  - QKVU (2-phase staged 128x128), P (8-phase 256x256), out (streaming TN=2): unchanged.

typedef __attribute__((ext_vector_type(8))) short short8;
typedef __attribute__((ext_vector_type(4))) short short4v;
typedef __attribute__((ext_vector_type(4))) float floatx4;

constexpr int HD = 768;
constexpr int TT = 2048;
constexpr long WElem = 589824;     // 768*768
constexpr long QKpb  = 1572864;    // 2048*768 shorts per batch
constexpr long Ppb   = 4194304;    // 2048*2048 shorts per batch

__device__ __forceinline__ short f2bf(float x) {
  unsigned u = __builtin_bit_cast(unsigned, x);
  u = u + 0x7fffu + ((u >> 16) & 1u);   // RNE
  return (short)(u >> 16);
}
__device__ __forceinline__ float bf2f(short s) {
  unsigned u = ((unsigned)(unsigned short)s) << 16;
  return __builtin_bit_cast(float, u);
}

// kf-major packed offset (in shorts) of element (i, c) of a row-major [R x C]
// matrix, KF = C/32. Layout: [strip = i>>6][kf = c>>5][frag mi = (i>>4)&3][512].
// Within-frag: lane = ((c&31)>>3)*16 + (i&15), elem = c&7.
__device__ __forceinline__ long pL(int i, int c, int KF) {
  return (((long)(i >> 6) * KF + (c >> 5)) * 4 + ((i >> 4) & 3)) * 512 +
         ((c & 31) >> 3) * 128 + (i & 15) * 8 + (c & 7);
}

typedef __attribute__((address_space(1))) void void_g;
typedef __attribute__((address_space(3))) void void_l;
__device__ __forceinline__ void gload16(const void* g, void* l) {
  __builtin_amdgcn_global_load_lds((const void_g*)g, (void_l*)l, 16, 0, 0);
}

// ---------------- preprocessing: 16-row slabs, whole-frag coalesced writes ---------
// blocks [0,512): LN slabs of x (16 rows each); [512,752): weight slabs; 752: bias.
// Write phase: wave w emits frags kf=w*6+j; lane supplies frag bytes lane*16..+15
// (= row lane&15, col-oct lane>>4) -> one 1KB coalesced burst per frag.
__global__ __launch_bounds__(256) void pre_kernel(
    const float* __restrict__ x, const float* __restrict__ g,
    const float* __restrict__ b, short* __restrict__ out,
    const float* __restrict__ wu, const float* __restrict__ wq,
    const float* __restrict__ wk, const float* __restrict__ wv,
    const float* __restrict__ wo,
    const float* __restrict__ bu, const float* __restrict__ bq,
    const float* __restrict__ bk, const float* __restrict__ bv,
    short* __restrict__ Wb, float* __restrict__ bcat) {
  int t = threadIdx.x;
  int bid = blockIdx.x;
  if (bid == 752) {                      // bias concat
#pragma unroll
    for (int j = 0; j < 12; j++) {
      int i = j * 256 + t;
      int which = i / HD, off = i - which * HD;
      const float* src = which == 0 ? bu : which == 1 ? bq : which == 2 ? bk : bv;
      bcat[i] = src[off];
    }
    return;
  }
  bool isLN = bid < 512;
  const float* src; short* dst; int rowbase;
  if (isLN) {
    rowbase = bid * 16; src = x + (long)rowbase * HD; dst = out;
  } else {
    int wb = bid - 512, which = wb / 48, rg = wb - which * 48;
    rowbase = rg * 16;
    src = (which == 0 ? wu : which == 1 ? wq : which == 2 ? wk
         : which == 3 ? wv : wo) + (long)rowbase * HD;
    dst = Wb + (long)which * WElem;
  }
  int lane = t & 63, w = t >> 6;
  __shared__ float stats[32];
  if (isLN) {
    int r = t >> 4, q = t & 15;          // 16 lanes per row
    float s = 0.f, ss = 0.f;
#pragma unroll
    for (int j = 0; j < 12; j++) {
      floatx4 v = *(const floatx4*)&src[(long)r * HD + q * 4 + j * 64];
#pragma unroll
      for (int e = 0; e < 4; e++) { s += v[e]; ss += v[e] * v[e]; }
    }
#pragma unroll
    for (int m = 1; m < 16; m <<= 1) {
      s += __shfl_xor(s, m); ss += __shfl_xor(ss, m);
    }
    if (q == 0) {
      float mean = s * (1.0f / HD);
      float var = ss * (1.0f / HD) - mean * mean;
      stats[r * 2] = mean;
      stats[r * 2 + 1] = rsqrtf(var + 1e-5f);
    }
    __syncthreads();
  }
  int oct = lane >> 4, i15 = lane & 15;
  float mean = 0.f, rstd = 1.f;
  if (isLN) { mean = stats[i15 * 2]; rstd = stats[i15 * 2 + 1]; }
  long strip = rowbase >> 6;
  int mi = (rowbase >> 4) & 3;
  const float* srow = src + (long)i15 * HD;   // L1/L2-hot re-read (LN) or first read (W)
#pragma unroll
  for (int j = 0; j < 6; j++) {
    int kf = w * 6 + j;
    int c0 = kf * 32 + oct * 8;
    floatx4 v0 = *(const floatx4*)&srow[c0];
    floatx4 v1 = *(const floatx4*)&srow[c0 + 4];
    short8 pk;
#pragma unroll
    for (int e = 0; e < 8; e++) {
      float v = e < 4 ? v0[e] : v1[e - 4];
      float o = (v - mean) * rstd;
      if (isLN) o = o * g[c0 + e] + b[c0 + e];
      pk[e] = f2bf(o);
    }
    *(short8*)&dst[((strip * 24 + (long)kf) * 4 + mi) * 512 + (long)lane * 8] = pk;
  }
}

// ---------------- 256x256 8-phase GEMM (P only) ------------------------------------
// 8 waves 2x4 (wm,wn); wave tile 128x64: acc[8][4]; BK=64 = 2 kf.
// LDS: A[p][strip 0..3][k 0..1][fi 0..3][1024B] at 0 / 32KB; B same at 64KB / 96KB.
template <int EPI, int KF, int GZ, int GY>
__global__ __launch_bounds__(512, 2) void wgemm8(
    const short* __restrict__ Ag, const short* __restrict__ Bg,
    long sAz, long sBz, short* __restrict__ o0) {
  constexpr int NT = KF / 2;                 // K-tiles
  constexpr int GYX = (GZ == 1) ? GY / 8 : GY / 2;
  int f = blockIdx.x;
  int xcd = f & 7, i = f >> 3;
  int bx = i / GYX, byo = i % GYX;
  int z, by;
  if constexpr (GZ == 1) { z = 0;        by = xcd * GYX + byo; }
  else                   { z = xcd >> 1; by = (xcd & 1) * GYX + byo; }

  int t = threadIdx.x, w = t >> 6, lane = t & 63;
  int wm = w >> 2, wn = w & 3;
  int qd = lane >> 4, l15 = lane & 15;
  int mf0 = by * 16 + wm * 8;                // frag-row base (16 frags/block)
  int nf0 = bx * 16 + wn * 4;                // frag-col base

  __shared__ __align__(16) char smem[131072];

  const char* Ab = (const char*)(Ag + (long)z * sAz);
  const char* Bb = (const char*)(Bg + (long)z * sBz);
  const char* aGt = Ab + ((long)(by * 4 + wm) * KF) * 4096 + wn * 1024 + lane * 16;
  const char* bGt = Bb + ((long)(bx * 4 + wm) * KF) * 4096 + wn * 1024 + lane * 16;
  char* ldsAst = smem + (wm * 8 + wn) * 1024;
  char* ldsBst = smem + 65536 + (wm * 8 + wn) * 1024;
  const char* rA = smem + wm * 16384 + lane * 16;
  const char* rB = smem + 65536 + wn * 8192 + lane * 16;

#define STG(which, p, k, kfg)                                                 \
  {                                                                           \
    const char* sb_ = (which) ? bGt : aGt;                                    \
    char* db_ = ((which) ? ldsBst : ldsAst) + (p) * 32768 + (k) * 4096;       \
    gload16(sb_ + (long)(kfg) * 4096, db_);                                   \
    gload16(sb_ + ((long)(2 * KF) + (kfg)) * 4096, db_ + 16384);              \
  }

#define PH(p, h, k, VM, ...)                                                  \
  {                                                                           \
    short8 aq[4];                                                             \
    if ((h) == 0) {                                                           \
      _Pragma("unroll") for (int ni = 0; ni < 4; ni++)                        \
          bq[ni] = *(const short8*)(rB + (p) * 32768 + (k) * 4096 + ni * 1024); \
    }                                                                         \
    _Pragma("unroll") for (int m2 = 0; m2 < 4; m2++)                          \
        aq[m2] = *(const short8*)(rA + (p) * 32768 + (h) * 8192 +             \
                                  (k) * 4096 + m2 * 1024);                    \
    __VA_ARGS__;                                                              \
    __builtin_amdgcn_s_barrier();                                             \
    asm volatile("s_waitcnt lgkmcnt(0)" ::: "memory");                        \
    __builtin_amdgcn_sched_barrier(0);                                        \
    __builtin_amdgcn_s_setprio(1);                                            \
    _Pragma("unroll") for (int ni = 0; ni < 4; ni++)                          \
      _Pragma("unroll") for (int m2 = 0; m2 < 4; m2++)                        \
          acc[(h) * 4 + m2][ni] = __builtin_amdgcn_mfma_f32_16x16x32_bf16(    \
              aq[m2], bq[ni], acc[(h) * 4 + m2][ni], 0, 0, 0);                \
    __builtin_amdgcn_s_setprio(0);                                            \
    __builtin_amdgcn_sched_barrier(0);                                        \
    VM;                                                                       \
    __builtin_amdgcn_s_barrier();                                             \
  }

  floatx4 acc[8][4] = {};
  short8 bq[4];

  STG(0, 0, 0, 0); STG(1, 0, 0, 0); STG(0, 0, 1, 1); STG(1, 0, 1, 1);
  asm volatile("s_waitcnt vmcnt(4)" ::: "memory");
  __builtin_amdgcn_s_barrier();

#pragma unroll 2
  for (int kt = 0; kt < NT - 1; ++kt) {
    int p = kt & 1, q = p ^ 1;
    int kfg = (kt + 1) * 2;
    PH(p, 0, 0, , STG(0, q, 0, kfg));
    PH(p, 1, 0, asm volatile("s_waitcnt vmcnt(4)" ::: "memory"), STG(1, q, 0, kfg));
    PH(p, 0, 1, , STG(0, q, 1, kfg + 1));
    PH(p, 1, 1, asm volatile("s_waitcnt vmcnt(4)" ::: "memory"), STG(1, q, 1, kfg + 1));
  }
  {
    int p = (NT - 1) & 1;
    PH(p, 0, 0, , );
    PH(p, 1, 0, asm volatile("s_waitcnt vmcnt(0)" ::: "memory"), );
    PH(p, 0, 1, , );
    PH(p, 1, 1, , );
  }
#undef PH
#undef STG

  // ---- epilogue (EPI==1): P = relu(S/sqrt(T))^2, packed vectorized store ----
  int qd4 = qd * 4;
  short* scw = (short*)(smem + w * 16384);   // 32 tiles x 512B
#pragma unroll
  for (int mi = 0; mi < 8; mi++)
#pragma unroll
    for (int ni = 0; ni < 4; ni++) {
      short* tile = scw + (mi * 4 + ni) * 256;
#pragma unroll
      for (int r = 0; r < 4; r++) {
        float v = acc[mi][ni][r];
        v *= 0.022097086912079608f;           // 1/sqrt(2048)
        v = fmaxf(v, 0.0f);
        v = v * v;
        tile[(qd4 + r) * 16 + (l15 ^ (((qd4 + r) & 4) << 1))] = f2bf(v);
      }
    }
  __syncthreads();
  int rw = lane & 15, g = (lane >> 4) & 1;
#pragma unroll
  for (int fp = 0; fp < 16; fp++) {
    int id = fp * 2 + (lane >> 5);
    int mi = id >> 2, ni = id & 3;
    const short* tile = scw + id * 256;
    short8 val = *(const short8*)&tile[rw * 16 + ((g ^ ((rw >> 2) & 1)) << 3)];
    int m = (mf0 + mi) * 16 + rw;
    int c0 = (nf0 + ni) * 16 + g * 8;
    *(short8*)&o0[(long)z * Ppb + pL(m, c0, 64)] = val;
  }
}

// ---------------- LDS-staged GEMM (m97 structure), EPI 0 (QKVU) / 2 (G) ------------
// 4 waves 2x2; wave tile (TM*16)x64; block (TM*32)x128. TM=4: QKVU; TM=2: G
// (64x128 tile -> 768 blocks = exactly 3 blocks/CU, zero packing tail).
template <int EPI, int KF, int GZ, int TM, int TN, int WN, int GY>
__global__ __launch_bounds__(256, 3) void wgemm(
    const short* __restrict__ Ag, const short* __restrict__ Bg,
    long sAz, long sBz,
    short* __restrict__ o0, short* __restrict__ o1,
    short* __restrict__ o2, short* __restrict__ o3,
    const float* __restrict__ bias, const short* __restrict__ umul) {
  constexpr int WM = 4 / WN;                 // 2
  constexpr int NSA = WM * TM / 4;           // A strips (TM=4: 2, TM=2: 1)
  constexpr int NSB = WN * TN / 4;           // 2 strips (BN = 128 cols)
  static_assert(TN == 4, "epilogue assumes TN=4");
  constexpr int LDSA_B = NSA * 4096 * 2;     // 2 buffers
  constexpr int LDSB_B = NSB * 4096 * 2;
  constexpr int SMEM_B = (LDSA_B + LDSB_B) < 32768 ? 32768 : (LDSA_B + LDSB_B);
  constexpr int GYX = (GZ == 1) ? GY / 8 : GY / 2;   // by-range per XCD
  int f = blockIdx.x;
  int xcd = f & 7, i = f >> 3;
  int bx = i / GYX, byo = i % GYX;
  int z, by;
  if constexpr (GZ == 1) { z = 0;        by = xcd * GYX + byo; }
  else                   { z = xcd >> 1; by = (xcd & 1) * GYX + byo; }

  int t = threadIdx.x, w = t >> 6, lane = t & 63;
  int qd = lane >> 4, l15 = lane & 15;
  int wm = w / WN, wn = w % WN;
  int mf0 = (by * WM + wm) * TM;               // frag-row index
  int nf0 = (bx * WN + wn) * TN;               // frag-col index

  __shared__ __align__(16) char smem[SMEM_B];

  const char* aG = (const char*)(Ag + (long)z * sAz) +
                   (long)(by * NSA) * KF * 4096 + w * 1024 + lane * 16;
  const char* bG = (const char*)(Bg + (long)z * sBz) +
                   (long)(bx * NSB) * KF * 4096 + w * 1024 + lane * 16;
  char* lA0 = smem + w * 1024;
  char* lB0 = smem + LDSA_B + w * 1024;

#define STAGE(p, kf)                                                          \
  {                                                                           \
    _Pragma("unroll") for (int s = 0; s < NSA; s++)                           \
        gload16(aG + ((long)s * KF + (kf)) * 4096,                            \
                lA0 + (p) * (NSA * 4096) + s * 4096);                         \
    _Pragma("unroll") for (int s = 0; s < NSB; s++)                           \
        gload16(bG + ((long)s * KF + (kf)) * 4096,                            \
                lB0 + (p) * (NSB * 4096) + s * 4096);                         \
  }

  floatx4 acc[TM][TN] = {};
  const char* fA = smem + (wm * TM) * 1024 + lane * 16;
  const char* fB = smem + LDSA_B + (wn * TN) * 1024 + lane * 16;

  STAGE(0, 0);
  __syncthreads();
#pragma unroll 2
  for (int kf = 0; kf < KF; ++kf) {
    int p = kf & 1;
    if (kf + 1 < KF) STAGE(p ^ 1, kf + 1);
    short8 a[TM], b[TN];
#pragma unroll
    for (int mi = 0; mi < TM; mi++)
      a[mi] = *(const short8*)(fA + p * (NSA * 4096) + mi * 1024);
#pragma unroll
    for (int ni = 0; ni < TN; ni++)
      b[ni] = *(const short8*)(fB + p * (NSB * 4096) + ni * 1024);
#pragma unroll
    for (int ni = 0; ni < TN; ni++)
#pragma unroll
      for (int mi = 0; mi < TM; mi++)
        acc[mi][ni] = __builtin_amdgcn_mfma_f32_16x16x32_bf16(
            a[mi], b[ni], acc[mi][ni], 0, 0, 0);
    __syncthreads();
  }
#undef STAGE

  // ---- epilogue ----
  int qd4 = qd * 4;
  if constexpr (EPI == 0) {
    static_assert(EPI != 0 || TM == 4, "EPI0 assumes TM=4");
    short* scw = (short*)(smem + w * 8192);        // 16 tiles x 512 B
    const bool vt = (bx >= 18);                    // which==3 (V): transposed tiles
#pragma unroll
    for (int mi = 0; mi < TM; mi++)
#pragma unroll
      for (int ni = 0; ni < TN; ni++) {
        int col = (nf0 + ni) * 16 + l15;
        short* tile = scw + (mi * TN + ni) * 256;
        short4v pk;
#pragma unroll
        for (int r = 0; r < 4; r++) {
          float v = acc[mi][ni][r];
          v += bias[col];
          v = v / (1.0f + __expf(-v));            // silu
          short sv = f2bf(v);
          if (!vt) tile[(qd4 + r) * 16 + (l15 ^ (((qd4 + r) & 4) << 1))] = sv;
          else pk[r] = sv;
        }
        if (vt)   // transposed tile[col][row]; rows qd4..qd4+3 contiguous -> b64
          *(short4v*)&tile[l15 * 16 + (qd4 ^ ((l15 & 4) << 1))] = pk;
      }
    __syncthreads();
    int rw = lane & 15, g = (lane >> 4) & 1;
#pragma unroll
    for (int fp = 0; fp < 8; fp++) {
      int id = fp * 2 + (lane >> 5);
      int mi = id >> 2, ni = id & 3;
      const short* tile = scw + id * 256;
      short8 val = *(const short8*)&tile[rw * 16 + ((g ^ ((rw >> 2) & 1)) << 3)];
      if (!vt) {
        int m = (mf0 + mi) * 16 + rw;
        int c0 = (nf0 + ni) * 16 + g * 8;
        int which = bx / 6;                      // block-uniform
        int d0 = c0 - which * HD;
        int batch = m >> 11, ii = m & (TT - 1);
        if (which == 0)      *(short8*)&o0[(long)m * HD + d0] = val;
        else if (which == 1) *(short8*)&o1[(long)batch * QKpb + pL(ii, d0, 24)] = val;
        else                 *(short8*)&o2[(long)batch * QKpb + pL(ii, d0, 24)] = val;
      } else {
        int d = (nf0 + ni) * 16 + rw - 3 * HD;   // tile row = original col
        int m0 = (mf0 + mi) * 16 + g * 8;        // 8 consecutive output rows
        int batch = m0 >> 11, ii0 = m0 & (TT - 1);
        *(short8*)&o3[(long)batch * QKpb + pL(d, ii0, 64)] = val;
      }
    }
  } else {
    // EPI 2: f32 scratch (no early rounding), TM/2 passes of 8 frags (8 KB/wave)
    float* scf = (float*)(smem + w * 8192);
#pragma unroll
    for (int half = 0; half < TM / 2; half++) {
#pragma unroll
      for (int mi2 = 0; mi2 < 2; mi2++)
#pragma unroll
        for (int ni = 0; ni < TN; ni++) {
          float* tile = scf + (mi2 * TN + ni) * 256;
          int mi = half * 2 + mi2;
#pragma unroll
          for (int r = 0; r < 4; r++)
            tile[(qd4 + r) * 16 + (l15 ^ (((qd4 + r) & 4) << 1))] = acc[mi][ni][r];
        }
      __syncthreads();
      int rw = lane & 15, g4 = lane >> 4;
#pragma unroll
      for (int cp = 0; cp < 8; cp++) {
        int mi = half * 2 + (cp >> 2), ni = cp & 3;
        const float* tile = scf + cp * 256;
        floatx4 val = *(const floatx4*)&tile[rw * 16 + ((g4 ^ (((rw >> 2) & 1) << 1)) << 2)];
        int m = (mf0 + mi) * 16 + rw;
        int c0 = (nf0 + ni) * 16 + g4 * 4;
        long gm = (long)z * TT + m;
        short4v u = *(const short4v*)&umul[gm * HD + c0];
        short4v gv;
#pragma unroll
        for (int j = 0; j < 4; j++) gv[j] = f2bf(val[j] * bf2f(u[j]));
        *(short4v*)&o0[pL((int)gm, c0, 24)] = gv;
      }
      __syncthreads();
    }
  }
}

// ---------------- barrier-free streaming GEMM (R0 verbatim) — 'out' only -----------
// 4 waves WM x WN; wave tile 64 x (TN*16); dist-2 ping-pong; ni-outer MFMA.
template <int KF, int TN, int WN, int GY>
__global__ __launch_bounds__(256, 3) void sgemm(
    const short* __restrict__ Ag, const short* __restrict__ Bg,
    float* __restrict__ outf, const float* __restrict__ bias) {
  constexpr int TM = 4;
  constexpr int GYX = GY / 8;                  // by-range per XCD
  int f = blockIdx.x;
  int xcd = f & 7, i = f >> 3;
  int bx = i / GYX, byo = i % GYX;
  int by = xcd * GYX + byo;

  int t = threadIdx.x, w = t >> 6, lane = t & 63;
  int qd = lane >> 4, l15 = lane & 15;
  int wm = w / WN, wn = w % WN;
  int mf0 = ((by * (4 / WN)) + wm) * TM;       // frag-row index (strip-aligned)
  int nf0 = (bx * WN + wn) * TN;               // frag-col index
  const short* aB = Ag + (long)(mf0 >> 2) * KF * 2048 + lane * 8;
  const short* bB = Bg + (long)(nf0 >> 2) * KF * 2048 + (nf0 & 3) * 512 + lane * 8;

  floatx4 acc[TM][TN] = {};
  short8 a[2][TM], b[2][TN];

#define LOADF(p, kf)                                                        \
  {                                                                         \
    _Pragma("unroll") for (int mi = 0; mi < TM; mi++)                       \
        a[p][mi] = *(const short8*)(aB + ((kf) * 4 + mi) * 512);            \
    _Pragma("unroll") for (int ni = 0; ni < TN; ni++)                       \
        b[p][ni] = *(const short8*)(bB + ((kf) * 4 + ni) * 512);            \
  }
#define MFMAS(p)                                                            \
  {                                                                         \
    _Pragma("unroll") for (int ni = 0; ni < TN; ni++)                       \
        _Pragma("unroll") for (int mi = 0; mi < TM; mi++)                   \
            acc[mi][ni] = __builtin_amdgcn_mfma_f32_16x16x32_bf16(          \
                a[p][mi], b[p][ni], acc[mi][ni], 0, 0, 0);                  \
  }

  LOADF(0, 0);
  LOADF(1, 1);
#pragma unroll 2
  for (int kf = 0; kf < KF; ++kf) {
    MFMAS(kf & 1);
    if (kf + 2 < KF) LOADF(kf & 1, kf + 2);   // refill the buffer just consumed
  }
#undef LOADF
#undef MFMAS

  // epilogue: lane holds D[row = qd*4+r][col = l15] per 16x16 frag
#pragma unroll
  for (int mi = 0; mi < TM; mi++)
#pragma unroll
    for (int ni = 0; ni < TN; ni++) {
      int mB = (mf0 + mi) * 16 + qd * 4;
      int col = (nf0 + ni) * 16 + l15;
#pragma unroll
      for (int r = 0; r < 4; r++) {
        int m = mB + r;
        outf[(long)m * HD + col] = acc[mi][ni][r] + bias[col];
      }
    }
}

extern "C" void kernel_launch(void* const* d_in, const int* in_sizes, int n_in,
                              void* d_out, int out_size, void* d_ws, size_t ws_size,
                              hipStream_t stream) {
  (void)in_sizes; (void)n_in; (void)out_size; (void)ws_size;
  const float* hid = (const float*)d_in[0];
  const float* lng = (const float*)d_in[1];
  const float* lnb = (const float*)d_in[2];
  const float* Wu  = (const float*)d_in[3];
  const float* bu  = (const float*)d_in[4];
  const float* Wq  = (const float*)d_in[5];
  const float* bq  = (const float*)d_in[6];
  const float* Wk  = (const float*)d_in[7];
  const float* bk  = (const float*)d_in[8];
  const float* Wv  = (const float*)d_in[9];
  const float* bv  = (const float*)d_in[10];
  const float* Wo  = (const float*)d_in[11];
  const float* bo  = (const float*)d_in[12];

  // workspace layout (bytes); packed buffers
  char* ws = (char*)d_ws;
  short* Wb   = (short*)(ws);                 // 5*589824 bf16 = 5,898,240 B (packed)
  float* bcat = (float*)(ws + 5898240);       // 3072 fp32     =    12,288 B
  short* xbf  = (short*)(ws + 5910528);       // x pack, 12,582,912 B
  short* Ub   = (short*)(ws + 18493440);      // U row-major, 12,582,912 B
  short* Qb   = (short*)(ws + 31076352);      // Q pack, 12,582,912 B
  short* Kb   = (short*)(ws + 43659264);      // K pack, 12,582,912 B
  short* Vt   = (short*)(ws + 56242176);      // Vt pack, 12,582,912 B
  short* Pb   = (short*)(ws + 68825088);      // P pack, 33,554,432 B
  short* Gb   = (short*)(ws + 102379520);     // G pack, 12,582,912 B (total ~115 MB)

  // preprocessing: [0,512) LN slabs, [512,752) weight slabs, 752 bias
  pre_kernel<<<753, 256, 0, stream>>>(hid, lng, lnb, xbf,
      Wu, Wq, Wk, Wv, Wo, bu, bq, bk, bv, Wb, bcat);

  // U,Q,K,V = silu(x @ Wcat^T + bcat): block 128x128 (2x2, TM=4), GY=64, GX=24
  wgemm<0, 24, 1, 4, 4, 2, 64><<<1536, 256, 0, stream>>>(
      xbf, Wb, 0, 0, Ub, Qb, Kb, Vt, bcat, nullptr);

  // P = relu(QK^T/sqrt(T))^2 per batch: 256x256 8-phase, GY=8, GX=8, GZ=4
  wgemm8<1, 24, 4, 8><<<256, 512, 0, stream>>>(
      Qb, Kb, QKpb, QKpb, Pb);

  // G = (P @ V) * U per batch: staged 64x128 (TM=2), GY=32, GX=6, GZ=4 -> 768 blocks
  wgemm<2, 64, 4, 2, 4, 2, 32><<<768, 256, 0, stream>>>(
      Pb, Vt, Ppb, QKpb, Gb, nullptr, nullptr, nullptr, nullptr, Ub);

  // out = G @ Wo^T + bo: STREAMING, block 128x64 (2x2, TN=2), GY=64, GX=12
  sgemm<24, 2, 2, 64><<<768, 256, 0, stream>>>(
      Gb, Wb + 4 * WElem, (float*)d_out, bo);
}

// Round 8
// 241.334 us; speedup vs baseline: 1.0780x; 1.0243x over previous
//
#include <hip/hip_runtime.h>
#include <math.h>

// GAU attention: LN -> silu(x@W^T+b) x4 -> P=relu^2(QK^T/sqrt(T)) -> AV=P@V -> (U*AV)@Wo^T+bo
// R19: P geometry fix (single variable). 8-phase 256x256 P ran 256 blocks x 128KB LDS
// = 1 block/CU = 2 waves/SIMD (weak latency hiding) + NT=12 fill/drain. 2-phase 128x128
// at __launch_bounds__(256,4) -> 4 blocks/CU: 1024 blocks = exactly one round, 16
// waves/CU (more TLP than QKVU's own proven config). LDS 4x32=128<=160KB, VGPR
// 4x56=224 per SIMD - both fit. EPI=1 epilogue restored verbatim from R13 (bit-identical).
//  - QKVU (2-phase 128x128 @3/CU), G (staged 64x128 TM=2 @768 blocks), out (streaming),
//    pre (16-row slab coalesced pack): unchanged from R18.

typedef __attribute__((ext_vector_type(8))) short short8;
typedef __attribute__((ext_vector_type(4))) short short4v;
typedef __attribute__((ext_vector_type(4))) float floatx4;

constexpr int HD = 768;
constexpr int TT = 2048;
constexpr long WElem = 589824;     // 768*768
constexpr long QKpb  = 1572864;    // 2048*768 shorts per batch
constexpr long Ppb   = 4194304;    // 2048*2048 shorts per batch

__device__ __forceinline__ short f2bf(float x) {
  unsigned u = __builtin_bit_cast(unsigned, x);
  u = u + 0x7fffu + ((u >> 16) & 1u);   // RNE
  return (short)(u >> 16);
}
__device__ __forceinline__ float bf2f(short s) {
  unsigned u = ((unsigned)(unsigned short)s) << 16;
  return __builtin_bit_cast(float, u);
}

// kf-major packed offset (in shorts) of element (i, c) of a row-major [R x C]
// matrix, KF = C/32. Layout: [strip = i>>6][kf = c>>5][frag mi = (i>>4)&3][512].
// Within-frag: lane = ((c&31)>>3)*16 + (i&15), elem = c&7.
__device__ __forceinline__ long pL(int i, int c, int KF) {
  return (((long)(i >> 6) * KF + (c >> 5)) * 4 + ((i >> 4) & 3)) * 512 +
         ((c & 31) >> 3) * 128 + (i & 15) * 8 + (c & 7);
}

typedef __attribute__((address_space(1))) void void_g;
typedef __attribute__((address_space(3))) void void_l;
__device__ __forceinline__ void gload16(const void* g, void* l) {
  __builtin_amdgcn_global_load_lds((const void_g*)g, (void_l*)l, 16, 0, 0);
}

// ---------------- preprocessing: 16-row slabs, whole-frag coalesced writes ---------
// blocks [0,512): LN slabs of x (16 rows each); [512,752): weight slabs; 752: bias.
__global__ __launch_bounds__(256) void pre_kernel(
    const float* __restrict__ x, const float* __restrict__ g,
    const float* __restrict__ b, short* __restrict__ out,
    const float* __restrict__ wu, const float* __restrict__ wq,
    const float* __restrict__ wk, const float* __restrict__ wv,
    const float* __restrict__ wo,
    const float* __restrict__ bu, const float* __restrict__ bq,
    const float* __restrict__ bk, const float* __restrict__ bv,
    short* __restrict__ Wb, float* __restrict__ bcat) {
  int t = threadIdx.x;
  int bid = blockIdx.x;
  if (bid == 752) {                      // bias concat
#pragma unroll
    for (int j = 0; j < 12; j++) {
      int i = j * 256 + t;
      int which = i / HD, off = i - which * HD;
      const float* src = which == 0 ? bu : which == 1 ? bq : which == 2 ? bk : bv;
      bcat[i] = src[off];
    }
    return;
  }
  bool isLN = bid < 512;
  const float* src; short* dst; int rowbase;
  if (isLN) {
    rowbase = bid * 16; src = x + (long)rowbase * HD; dst = out;
  } else {
    int wb = bid - 512, which = wb / 48, rg = wb - which * 48;
    rowbase = rg * 16;
    src = (which == 0 ? wu : which == 1 ? wq : which == 2 ? wk
         : which == 3 ? wv : wo) + (long)rowbase * HD;
    dst = Wb + (long)which * WElem;
  }
  int lane = t & 63, w = t >> 6;
  __shared__ float stats[32];
  if (isLN) {
    int r = t >> 4, q = t & 15;          // 16 lanes per row
    float s = 0.f, ss = 0.f;
#pragma unroll
    for (int j = 0; j < 12; j++) {
      floatx4 v = *(const floatx4*)&src[(long)r * HD + q * 4 + j * 64];
#pragma unroll
      for (int e = 0; e < 4; e++) { s += v[e]; ss += v[e] * v[e]; }
    }
#pragma unroll
    for (int m = 1; m < 16; m <<= 1) {
      s += __shfl_xor(s, m); ss += __shfl_xor(ss, m);
    }
    if (q == 0) {
      float mean = s * (1.0f / HD);
      float var = ss * (1.0f / HD) - mean * mean;
      stats[r * 2] = mean;
      stats[r * 2 + 1] = rsqrtf(var + 1e-5f);
    }
    __syncthreads();
  }
  int oct = lane >> 4, i15 = lane & 15;
  float mean = 0.f, rstd = 1.f;
  if (isLN) { mean = stats[i15 * 2]; rstd = stats[i15 * 2 + 1]; }
  long strip = rowbase >> 6;
  int mi = (rowbase >> 4) & 3;
  const float* srow = src + (long)i15 * HD;   // L1/L2-hot re-read (LN) or first read (W)
#pragma unroll
  for (int j = 0; j < 6; j++) {
    int kf = w * 6 + j;
    int c0 = kf * 32 + oct * 8;
    floatx4 v0 = *(const floatx4*)&srow[c0];
    floatx4 v1 = *(const floatx4*)&srow[c0 + 4];
    short8 pk;
#pragma unroll
    for (int e = 0; e < 8; e++) {
      float v = e < 4 ? v0[e] : v1[e - 4];
      float o = (v - mean) * rstd;
      if (isLN) o = o * g[c0 + e] + b[c0 + e];
      pk[e] = f2bf(o);
    }
    *(short8*)&dst[((strip * 24 + (long)kf) * 4 + mi) * 512 + (long)lane * 8] = pk;
  }
}

// ---------------- LDS-staged GEMM (m97 structure), EPI 0 (QKVU) / 1 (P) / 2 (G) ----
// 4 waves 2x2; wave tile (TM*16)x64; block (TM*32)x128. OCC = min waves/EU
// (= blocks/CU for 256-thread blocks).
template <int EPI, int KF, int GZ, int TM, int TN, int WN, int GY, int OCC>
__global__ __launch_bounds__(256, OCC) void wgemm(
    const short* __restrict__ Ag, const short* __restrict__ Bg,
    long sAz, long sBz,
    short* __restrict__ o0, short* __restrict__ o1,
    short* __restrict__ o2, short* __restrict__ o3,
    const float* __restrict__ bias, const short* __restrict__ umul) {
  constexpr int WM = 4 / WN;                 // 2
  constexpr int NSA = WM * TM / 4;           // A strips (TM=4: 2, TM=2: 1)
  constexpr int NSB = WN * TN / 4;           // 2 strips (BN = 128 cols)
  static_assert(TN == 4, "epilogue assumes TN=4");
  constexpr int LDSA_B = NSA * 4096 * 2;     // 2 buffers
  constexpr int LDSB_B = NSB * 4096 * 2;
  constexpr int SMEM_B = (LDSA_B + LDSB_B) < 32768 ? 32768 : (LDSA_B + LDSB_B);
  constexpr int GYX = (GZ == 1) ? GY / 8 : GY / 2;   // by-range per XCD
  int f = blockIdx.x;
  int xcd = f & 7, i = f >> 3;
  int bx = i / GYX, byo = i % GYX;
  int z, by;
  if constexpr (GZ == 1) { z = 0;        by = xcd * GYX + byo; }
  else                   { z = xcd >> 1; by = (xcd & 1) * GYX + byo; }

  int t = threadIdx.x, w = t >> 6, lane = t & 63;
  int qd = lane >> 4, l15 = lane & 15;
  int wm = w / WN, wn = w % WN;
  int mf0 = (by * WM + wm) * TM;               // frag-row index
  int nf0 = (bx * WN + wn) * TN;               // frag-col index

  __shared__ __align__(16) char smem[SMEM_B];

  const char* aG = (const char*)(Ag + (long)z * sAz) +
                   (long)(by * NSA) * KF * 4096 + w * 1024 + lane * 16;
  const char* bG = (const char*)(Bg + (long)z * sBz) +
                   (long)(bx * NSB) * KF * 4096 + w * 1024 + lane * 16;
  char* lA0 = smem + w * 1024;
  char* lB0 = smem + LDSA_B + w * 1024;

#define STAGE(p, kf)                                                          \
  {                                                                           \
    _Pragma("unroll") for (int s = 0; s < NSA; s++)                           \
        gload16(aG + ((long)s * KF + (kf)) * 4096,                            \
                lA0 + (p) * (NSA * 4096) + s * 4096);                         \
    _Pragma("unroll") for (int s = 0; s < NSB; s++)                           \
        gload16(bG + ((long)s * KF + (kf)) * 4096,                            \
                lB0 + (p) * (NSB * 4096) + s * 4096);                         \
  }

  floatx4 acc[TM][TN] = {};
  const char* fA = smem + (wm * TM) * 1024 + lane * 16;
  const char* fB = smem + LDSA_B + (wn * TN) * 1024 + lane * 16;

  STAGE(0, 0);
  __syncthreads();
#pragma unroll 2
  for (int kf = 0; kf < KF; ++kf) {
    int p = kf & 1;
    if (kf + 1 < KF) STAGE(p ^ 1, kf + 1);
    short8 a[TM], b[TN];
#pragma unroll
    for (int mi = 0; mi < TM; mi++)
      a[mi] = *(const short8*)(fA + p * (NSA * 4096) + mi * 1024);
#pragma unroll
    for (int ni = 0; ni < TN; ni++)
      b[ni] = *(const short8*)(fB + p * (NSB * 4096) + ni * 1024);
#pragma unroll
    for (int ni = 0; ni < TN; ni++)
#pragma unroll
      for (int mi = 0; mi < TM; mi++)
        acc[mi][ni] = __builtin_amdgcn_mfma_f32_16x16x32_bf16(
            a[mi], b[ni], acc[mi][ni], 0, 0, 0);
    __syncthreads();
  }
#undef STAGE

  // ---- epilogue ----
  int qd4 = qd * 4;
  if constexpr (EPI <= 1) {
    static_assert(EPI > 1 || TM == 4, "EPI0/1 assume TM=4");
    short* scw = (short*)(smem + w * 8192);        // 16 tiles x 512 B
    const bool vt = (EPI == 0) && (bx >= 18);      // which==3 (V): transposed tiles
#pragma unroll
    for (int mi = 0; mi < TM; mi++)
#pragma unroll
      for (int ni = 0; ni < TN; ni++) {
        int col = (nf0 + ni) * 16 + l15;
        short* tile = scw + (mi * TN + ni) * 256;
        short4v pk;
#pragma unroll
        for (int r = 0; r < 4; r++) {
          float v = acc[mi][ni][r];
          if constexpr (EPI == 0) {
            v += bias[col];
            v = v / (1.0f + __expf(-v));            // silu
          } else {
            v *= 0.022097086912079608f;             // 1/sqrt(2048)
            v = fmaxf(v, 0.0f);
            v = v * v;
          }
          short sv = f2bf(v);
          if (!vt) tile[(qd4 + r) * 16 + (l15 ^ (((qd4 + r) & 4) << 1))] = sv;
          else pk[r] = sv;
        }
        if (vt)   // transposed tile[col][row]; rows qd4..qd4+3 contiguous -> b64
          *(short4v*)&tile[l15 * 16 + (qd4 ^ ((l15 & 4) << 1))] = pk;
      }
    __syncthreads();
    int rw = lane & 15, g = (lane >> 4) & 1;
#pragma unroll
    for (int fp = 0; fp < 8; fp++) {
      int id = fp * 2 + (lane >> 5);
      int mi = id >> 2, ni = id & 3;
      const short* tile = scw + id * 256;
      short8 val = *(const short8*)&tile[rw * 16 + ((g ^ ((rw >> 2) & 1)) << 3)];
      if constexpr (EPI == 1) {
        int m = (mf0 + mi) * 16 + rw;
        int c0 = (nf0 + ni) * 16 + g * 8;
        *(short8*)&o0[(long)z * Ppb + pL(m, c0, 64)] = val;
      } else if (!vt) {
        int m = (mf0 + mi) * 16 + rw;
        int c0 = (nf0 + ni) * 16 + g * 8;
        int which = bx / 6;                      // block-uniform
        int d0 = c0 - which * HD;
        int batch = m >> 11, ii = m & (TT - 1);
        if (which == 0)      *(short8*)&o0[(long)m * HD + d0] = val;
        else if (which == 1) *(short8*)&o1[(long)batch * QKpb + pL(ii, d0, 24)] = val;
        else                 *(short8*)&o2[(long)batch * QKpb + pL(ii, d0, 24)] = val;
      } else {
        int d = (nf0 + ni) * 16 + rw - 3 * HD;   // tile row = original col
        int m0 = (mf0 + mi) * 16 + g * 8;        // 8 consecutive output rows
        int batch = m0 >> 11, ii0 = m0 & (TT - 1);
        *(short8*)&o3[(long)batch * QKpb + pL(d, ii0, 64)] = val;
      }
    }
  } else {
    // EPI 2: f32 scratch (no early rounding), TM/2 passes of 8 frags (8 KB/wave)
    float* scf = (float*)(smem + w * 8192);
#pragma unroll
    for (int half = 0; half < TM / 2; half++) {
#pragma unroll
      for (int mi2 = 0; mi2 < 2; mi2++)
#pragma unroll
        for (int ni = 0; ni < TN; ni++) {
          float* tile = scf + (mi2 * TN + ni) * 256;
          int mi = half * 2 + mi2;
#pragma unroll
          for (int r = 0; r < 4; r++)
            tile[(qd4 + r) * 16 + (l15 ^ (((qd4 + r) & 4) << 1))] = acc[mi][ni][r];
        }
      __syncthreads();
      int rw = lane & 15, g4 = lane >> 4;
#pragma unroll
      for (int cp = 0; cp < 8; cp++) {
        int mi = half * 2 + (cp >> 2), ni = cp & 3;
        const float* tile = scf + cp * 256;
        floatx4 val = *(const floatx4*)&tile[rw * 16 + ((g4 ^ (((rw >> 2) & 1) << 1)) << 2)];
        int m = (mf0 + mi) * 16 + rw;
        int c0 = (nf0 + ni) * 16 + g4 * 4;
        long gm = (long)z * TT + m;
        short4v u = *(const short4v*)&umul[gm * HD + c0];
        short4v gv;
#pragma unroll
        for (int j = 0; j < 4; j++) gv[j] = f2bf(val[j] * bf2f(u[j]));
        *(short4v*)&o0[pL((int)gm, c0, 24)] = gv;
      }
      __syncthreads();
    }
  }
}

// ---------------- barrier-free streaming GEMM (R0 verbatim) — 'out' only -----------
// 4 waves WM x WN; wave tile 64 x (TN*16); dist-2 ping-pong; ni-outer MFMA.
template <int KF, int TN, int WN, int GY>
__global__ __launch_bounds__(256, 3) void sgemm(
    const short* __restrict__ Ag, const short* __restrict__ Bg,
    float* __restrict__ outf, const float* __restrict__ bias) {
  constexpr int TM = 4;
  constexpr int GYX = GY / 8;                  // by-range per XCD
  int f = blockIdx.x;
  int xcd = f & 7, i = f >> 3;
  int bx = i / GYX, byo = i % GYX;
  int by = xcd * GYX + byo;

  int t = threadIdx.x, w = t >> 6, lane = t & 63;
  int qd = lane >> 4, l15 = lane & 15;
  int wm = w / WN, wn = w % WN;
  int mf0 = ((by * (4 / WN)) + wm) * TM;       // frag-row index (strip-aligned)
  int nf0 = (bx * WN + wn) * TN;               // frag-col index
  const short* aB = Ag + (long)(mf0 >> 2) * KF * 2048 + lane * 8;
  const short* bB = Bg + (long)(nf0 >> 2) * KF * 2048 + (nf0 & 3) * 512 + lane * 8;

  floatx4 acc[TM][TN] = {};
  short8 a[2][TM], b[2][TN];

#define LOADF(p, kf)                                                        \
  {                                                                         \
    _Pragma("unroll") for (int mi = 0; mi < TM; mi++)                       \
        a[p][mi] = *(const short8*)(aB + ((kf) * 4 + mi) * 512);            \
    _Pragma("unroll") for (int ni = 0; ni < TN; ni++)                       \
        b[p][ni] = *(const short8*)(bB + ((kf) * 4 + ni) * 512);            \
  }
#define MFMAS(p)                                                            \
  {                                                                         \
    _Pragma("unroll") for (int ni = 0; ni < TN; ni++)                       \
        _Pragma("unroll") for (int mi = 0; mi < TM; mi++)                   \
            acc[mi][ni] = __builtin_amdgcn_mfma_f32_16x16x32_bf16(          \
                a[p][mi], b[p][ni], acc[mi][ni], 0, 0, 0);                  \
  }

  LOADF(0, 0);
  LOADF(1, 1);
#pragma unroll 2
  for (int kf = 0; kf < KF; ++kf) {
    MFMAS(kf & 1);
    if (kf + 2 < KF) LOADF(kf & 1, kf + 2);   // refill the buffer just consumed
  }
#undef LOADF
#undef MFMAS

  // epilogue: lane holds D[row = qd*4+r][col = l15] per 16x16 frag
#pragma unroll
  for (int mi = 0; mi < TM; mi++)
#pragma unroll
    for (int ni = 0; ni < TN; ni++) {
      int mB = (mf0 + mi) * 16 + qd * 4;
      int col = (nf0 + ni) * 16 + l15;
#pragma unroll
      for (int r = 0; r < 4; r++) {
        int m = mB + r;
        outf[(long)m * HD + col] = acc[mi][ni][r] + bias[col];
      }
    }
}

extern "C" void kernel_launch(void* const* d_in, const int* in_sizes, int n_in,
                              void* d_out, int out_size, void* d_ws, size_t ws_size,
                              hipStream_t stream) {
  (void)in_sizes; (void)n_in; (void)out_size; (void)ws_size;
  const float* hid = (const float*)d_in[0];
  const float* lng = (const float*)d_in[1];
  const float* lnb = (const float*)d_in[2];
  const float* Wu  = (const float*)d_in[3];
  const float* bu  = (const float*)d_in[4];
  const float* Wq  = (const float*)d_in[5];
  const float* bq  = (const float*)d_in[6];
  const float* Wk  = (const float*)d_in[7];
  const float* bk  = (const float*)d_in[8];
  const float* Wv  = (const float*)d_in[9];
  const float* bv  = (const float*)d_in[10];
  const float* Wo  = (const float*)d_in[11];
  const float* bo  = (const float*)d_in[12];

  // workspace layout (bytes); packed buffers
  char* ws = (char*)d_ws;
  short* Wb   = (short*)(ws);                 // 5*589824 bf16 = 5,898,240 B (packed)
  float* bcat = (float*)(ws + 5898240);       // 3072 fp32     =    12,288 B
  short* xbf  = (short*)(ws + 5910528);       // x pack, 12,582,912 B
  short* Ub   = (short*)(ws + 18493440);      // U row-major, 12,582,912 B
  short* Qb   = (short*)(ws + 31076352);      // Q pack, 12,582,912 B
  short* Kb   = (short*)(ws + 43659264);      // K pack, 12,582,912 B
  short* Vt   = (short*)(ws + 56242176);      // Vt pack, 12,582,912 B
  short* Pb   = (short*)(ws + 68825088);      // P pack, 33,554,432 B
  short* Gb   = (short*)(ws + 102379520);     // G pack, 12,582,912 B (total ~115 MB)

  // preprocessing: [0,512) LN slabs, [512,752) weight slabs, 752 bias
  pre_kernel<<<753, 256, 0, stream>>>(hid, lng, lnb, xbf,
      Wu, Wq, Wk, Wv, Wo, bu, bq, bk, bv, Wb, bcat);

  // U,Q,K,V = silu(x @ Wcat^T + bcat): block 128x128 (TM=4) @3/CU, GY=64, GX=24
  wgemm<0, 24, 1, 4, 4, 2, 64, 3><<<1536, 256, 0, stream>>>(
      xbf, Wb, 0, 0, Ub, Qb, Kb, Vt, bcat, nullptr);

  // P = relu(QK^T/sqrt(T))^2 per batch: 2-phase 128x128 @4/CU (1024 blocks = exactly
  // one round, 16 waves/CU), GY=16, GX=16, GZ=4
  wgemm<1, 24, 4, 4, 4, 2, 16, 4><<<1024, 256, 0, stream>>>(
      Qb, Kb, QKpb, QKpb, Pb, nullptr, nullptr, nullptr, nullptr, nullptr);

  // G = (P @ V) * U per batch: staged 64x128 (TM=2) @3/CU, GY=32, GX=6, GZ=4 -> 768
  wgemm<2, 64, 4, 2, 4, 2, 32, 3><<<768, 256, 0, stream>>>(
      Pb, Vt, Ppb, QKpb, Gb, nullptr, nullptr, nullptr, nullptr, Ub);

  // out = G @ Wo^T + bo: STREAMING, block 128x64 (2x2, TN=2), GY=64, GX=12
  sgemm<24, 2, 2, 64><<<768, 256, 0, stream>>>(
      Gb, Wb + 4 * WElem, (float*)d_out, bo);
}